// Round 1
// baseline (12112.297 us; speedup 1.0000x reference)
//
#include <hip/hip_runtime.h>
#include <hip/hip_bf16.h>
#include <math.h>

// Problem constants (GRUAttnDecoder): B=16, ENC=512, T=64, DIM=768, VOCAB=21128
#define Bdim 16
#define ENC 512
#define Tn 64
#define DIM 768
#define VOCAB 21128
#define SCALEF 0.03608439182435161f  // 1/sqrt(768)
#define NEGF   -1e30f

// ws layout (floats):
//   P_ru   : 1024*1536   gate preacts r|u (bias+emb precomputed, attn/h atomic-added)
//   P_c    : 1024*768    gate preact c
//   h_all  : 65*16*768   h state slots 0..64 (slot 0 = init_h broadcast)
//   attn   : 16*768      attention context vector (per step, overwritten)
//   out_all: 1024*768    h_new @ W_out^T + b_out
//   copyq  : 1024*768    h_new @ W_copy^T + b_copy
//   S      : 1024        sum_v exp(logit) per (t,b) row
//   cnum   : 1024        sum of exp(copy_logit) over s with ids==tgt
//   cden   : 1024        sum of exp(copy_logit) over all s
//   loss   : 2           {sum, count}
// total = 4,746,242 floats = 18.99 MB

__device__ __forceinline__ float wred_sum(float v) {
#pragma unroll
  for (int m = 32; m >= 1; m >>= 1) v += __shfl_xor(v, m, 64);
  return v;
}
__device__ __forceinline__ float sigmf(float x) { return 1.0f / (1.0f + __expf(-x)); }

// ---------------- init ----------------
__global__ void k_zero(float* __restrict__ p, int n) {
  int i = blockIdx.x * blockDim.x + threadIdx.x;
  int stride = gridDim.x * blockDim.x;
  for (; i < n; i += stride) p[i] = 0.0f;
}

__global__ void k_h0(const float* __restrict__ init_h, float* __restrict__ h_all) {
  int i = blockIdx.x * blockDim.x + threadIdx.x;
  if (i < Bdim * DIM) h_all[i] = init_h[i % DIM];
}

// ---- precompute emb-part of gate preactivations + bias for all (t,b) ----
// grid (9, 64) x 256 : n = 0..2303 outputs, 16 rows per block
__global__ void __launch_bounds__(256) k_pre(
    const int* __restrict__ din, const float* __restrict__ emb,
    const float* __restrict__ Wr, const float* __restrict__ br,
    const float* __restrict__ Wu, const float* __restrict__ bu,
    const float* __restrict__ Wc, const float* __restrict__ bc,
    float* __restrict__ P_ru, float* __restrict__ P_c) {
  const int nb = blockIdx.x, tbc = blockIdx.y;
  const int n = nb * 256 + threadIdx.x;
  const float* wrow;
  float bias;
  if (n < 768)       { wrow = Wr + n * 2304 + 768;          bias = br[n]; }
  else if (n < 1536) { wrow = Wu + (n - 768) * 2304 + 768;  bias = bu[n - 768]; }
  else               { wrow = Wc + (n - 1536) * 2304 + 768; bias = bc[n - 1536]; }
  int id[16];
#pragma unroll
  for (int i = 0; i < 16; ++i) {
    int row = tbc * 16 + i;                 // row = t*16 + b
    id[i] = din[(row & 15) * Tn + (row >> 4)];
  }
  float acc[16];
#pragma unroll
  for (int i = 0; i < 16; ++i) acc[i] = bias;
  for (int k = 0; k < DIM; k += 4) {
    float4 w = *(const float4*)(wrow + k);
#pragma unroll
    for (int i = 0; i < 16; ++i) {
      float4 x = *(const float4*)(emb + (size_t)id[i] * DIM + k);  // uniform -> s_load
      acc[i] = fmaf(w.x, x.x, fmaf(w.y, x.y, fmaf(w.z, x.z, fmaf(w.w, x.w, acc[i]))));
    }
  }
#pragma unroll
  for (int i = 0; i < 16; ++i) {
    int row = tbc * 16 + i;
    if (n < 1536) P_ru[(size_t)row * 1536 + n] = acc[i];
    else          P_c[(size_t)row * 768 + (n - 1536)] = acc[i];
  }
}

// ---- per-step: finalize h(slot t) from step t-1, then attention ----
// grid 16 (one block per batch) x 512
__global__ void __launch_bounds__(512) k_attn(
    int t, const float* __restrict__ ctx, const float* __restrict__ mask,
    const float* __restrict__ P_ru, const float* __restrict__ P_c,
    float* __restrict__ h_all, float* __restrict__ attn_vec) {
  const int b = blockIdx.x;
  const int tid = threadIdx.x;
  __shared__ float e_lds[ENC];
  __shared__ float red[8];
  if (t > 0) {
    const int rowp = (t - 1) * Bdim + b;
    for (int j = tid; j < DIM; j += 512) {
      float u = sigmf(P_ru[(size_t)rowp * 1536 + 768 + j]);
      float c = tanhf(P_c[(size_t)rowp * 768 + j]);
      float hp = h_all[(size_t)rowp * DIM + j];
      h_all[(size_t)(t * Bdim + b) * DIM + j] = hp + u * (c - hp);
    }
  }
  __syncthreads();
  // scores (one s per thread)
  const float* hb = h_all + (size_t)(t * Bdim + b) * DIM;
  const int s = tid;
  const float* crow = ctx + ((size_t)(b * ENC + s)) * DIM;
  float dot = 0.f;
  for (int k = 0; k < DIM; k += 4) {
    float4 c4 = *(const float4*)(crow + k);
    float4 h4 = *(const float4*)(hb + k);  // broadcast load
    dot = fmaf(c4.x, h4.x, fmaf(c4.y, h4.y, fmaf(c4.z, h4.z, fmaf(c4.w, h4.w, dot))));
  }
  float madd = (1.0f - mask[b * ENC + s]) * NEGF;
  float e = __expf(fmaf(dot, SCALEF, madd));  // scores ~O(1): no max-sub needed
  e_lds[s] = e;
  float de = wred_sum(e);
  if ((tid & 63) == 0) red[tid >> 6] = de;
  __syncthreads();
  float den = 0.f;
#pragma unroll
  for (int w = 0; w < 8; ++w) den += red[w];
  float inv = 1.0f / den;
  // attn_vec (d per thread, coalesced over threads)
  float a1 = 0.f, a2 = 0.f;
  const int d1 = tid, d2 = tid + 512;
  for (int ss = 0; ss < ENC; ++ss) {
    float w = e_lds[ss];
    const float* cr = ctx + ((size_t)(b * ENC + ss)) * DIM;
    a1 = fmaf(w, cr[d1], a1);
    if (d2 < DIM) a2 = fmaf(w, cr[d2], a2);
  }
  attn_vec[b * DIM + d1] = a1 * inv;
  if (d2 < DIM) attn_vec[b * DIM + d2] = a2 * inv;
}

// ---- per-step: r,u preacts (attn & h parts), K-split, atomic into P_ru ----
// grid (6, 16) x 256
__global__ void __launch_bounds__(256) k_ru(
    int t, const float* __restrict__ Wr, const float* __restrict__ Wu,
    const float* __restrict__ attn_vec, const float* __restrict__ h_all,
    float* __restrict__ P_ru) {
  const int jb = blockIdx.x, ks = blockIdx.y;
  const int j = jb * 256 + threadIdx.x;  // 0..1535
  const float* wrow = (j < 768) ? (Wr + (size_t)j * 2304) : (Wu + (size_t)(j - 768) * 2304);
  const float* xbase;
  int wcol, xoff;
  if (ks < 8) { xbase = attn_vec;                          wcol = ks * 96;              xoff = ks * 96; }
  else        { xbase = h_all + (size_t)(t * Bdim) * DIM;  wcol = 1536 + (ks - 8) * 96; xoff = (ks - 8) * 96; }
  float acc[16];
#pragma unroll
  for (int i = 0; i < 16; ++i) acc[i] = 0.f;
  for (int kk = 0; kk < 96; kk += 4) {
    float4 w = *(const float4*)(wrow + wcol + kk);
#pragma unroll
    for (int bb = 0; bb < 16; ++bb) {
      float4 x = *(const float4*)(xbase + bb * DIM + xoff + kk);  // uniform -> s_load
      acc[bb] = fmaf(w.x, x.x, fmaf(w.y, x.y, fmaf(w.z, x.z, fmaf(w.w, x.w, acc[bb]))));
    }
  }
#pragma unroll
  for (int bb = 0; bb < 16; ++bb)
    atomicAdd(&P_ru[(size_t)(t * Bdim + bb) * 1536 + j], acc[bb]);
}

// ---- per-step: c preact (attn & r*h parts), K-split, atomic into P_c ----
// grid (3, 16) x 256
__global__ void __launch_bounds__(256) k_c(
    int t, const float* __restrict__ Wc,
    const float* __restrict__ attn_vec, const float* __restrict__ h_all,
    const float* __restrict__ P_ru, float* __restrict__ P_c) {
  const int jb = blockIdx.x, ks = blockIdx.y;
  const int j = jb * 256 + threadIdx.x;  // 0..767
  const float* wrow = Wc + (size_t)j * 2304;
  __shared__ float x_lds[16][96];
  float acc[16];
#pragma unroll
  for (int i = 0; i < 16; ++i) acc[i] = 0.f;
  if (ks < 8) {
    const int c0 = ks * 96;
    for (int kk = 0; kk < 96; kk += 4) {
      float4 w = *(const float4*)(wrow + c0 + kk);
#pragma unroll
      for (int bb = 0; bb < 16; ++bb) {
        float4 x = *(const float4*)(attn_vec + bb * DIM + c0 + kk);  // uniform -> s_load
        acc[bb] = fmaf(w.x, x.x, fmaf(w.y, x.y, fmaf(w.z, x.z, fmaf(w.w, x.w, acc[bb]))));
      }
    }
  } else {
    const int m0 = (ks - 8) * 96;
    for (int idx = threadIdx.x; idx < 16 * 96; idx += 256) {
      int bb = idx / 96, kk = idx % 96;
      int row = t * Bdim + bb;
      float r = sigmf(P_ru[(size_t)row * 1536 + m0 + kk]);  // r occupies cols [0,768)
      x_lds[bb][kk] = r * h_all[(size_t)row * DIM + m0 + kk];
    }
    __syncthreads();
    const int wcol = 1536 + m0;
    for (int kk = 0; kk < 96; kk += 4) {
      float4 w = *(const float4*)(wrow + wcol + kk);
#pragma unroll
      for (int bb = 0; bb < 16; ++bb) {
        float4 x = *(const float4*)&x_lds[bb][kk];
        acc[bb] = fmaf(w.x, x.x, fmaf(w.y, x.y, fmaf(w.z, x.z, fmaf(w.w, x.w, acc[bb]))));
      }
    }
  }
#pragma unroll
  for (int bb = 0; bb < 16; ++bb)
    atomicAdd(&P_c[(size_t)(t * Bdim + bb) * 768 + j], acc[bb]);
}

// ---- finalize last h (slot 64) ----
__global__ void k_hfin(const float* __restrict__ P_ru, const float* __restrict__ P_c,
                       float* __restrict__ h_all) {
  const int b = blockIdx.x;
  const int rowp = (Tn - 1) * Bdim + b;
  for (int j = threadIdx.x; j < DIM; j += 256) {
    float u = sigmf(P_ru[(size_t)rowp * 1536 + 768 + j]);
    float c = tanhf(P_c[(size_t)rowp * 768 + j]);
    float hp = h_all[(size_t)rowp * DIM + j];
    h_all[(size_t)(Tn * Bdim + b) * DIM + j] = hp + u * (c - hp);
  }
}

// ---- deferred: out_all & copyq for all 1024 rows ----
// grid (6, 64) x 256
__global__ void __launch_bounds__(256) k_out(
    const float* __restrict__ Wo, const float* __restrict__ bo,
    const float* __restrict__ Wcp, const float* __restrict__ bcp,
    const float* __restrict__ h_all, float* __restrict__ out_all,
    float* __restrict__ copyq) {
  const int nb = blockIdx.x, tbc = blockIdx.y;
  const int n = nb * 256 + threadIdx.x;  // 0..1535
  const float* wrow;
  float bias;
  if (n < 768) { wrow = Wo + (size_t)n * 768;          bias = bo[n]; }
  else         { wrow = Wcp + (size_t)(n - 768) * 768; bias = bcp[n - 768]; }
  const float* hbase = h_all + (size_t)(tbc * 16 + 16) * DIM;  // h_new rows = slot t+1
  float acc[16];
#pragma unroll
  for (int i = 0; i < 16; ++i) acc[i] = bias;
  for (int k = 0; k < DIM; k += 4) {
    float4 w = *(const float4*)(wrow + k);
#pragma unroll
    for (int i = 0; i < 16; ++i) {
      float4 x = *(const float4*)(hbase + i * DIM + k);  // uniform -> s_load
      acc[i] = fmaf(w.x, x.x, fmaf(w.y, x.y, fmaf(w.z, x.z, fmaf(w.w, x.w, acc[i]))));
    }
  }
#pragma unroll
  for (int i = 0; i < 16; ++i) {
    int row = tbc * 16 + i;
    if (n < 768) out_all[(size_t)row * 768 + n] = acc[i];
    else         copyq[(size_t)row * 768 + (n - 768)] = acc[i];
  }
}

// ---- deferred: copy softmax num/den per (t,b). ctx rows live in VGPRs across t ----
// grid (8, 16) x 512 : wave = k-segment (96), lane = s within 64-chunk
__global__ void __launch_bounds__(512) k_copy(
    const int* __restrict__ ids, const int* __restrict__ dtg,
    const float* __restrict__ ctx, const float* __restrict__ mask,
    const float* __restrict__ copyq,
    float* __restrict__ cnum, float* __restrict__ cden) {
  const int sc = blockIdx.x, b = blockIdx.y;
  const int lane = threadIdx.x & 63;
  const int seg = __builtin_amdgcn_readfirstlane(threadIdx.x >> 6);  // 0..7, SGPR
  const int s = sc * 64 + lane;
  __shared__ float part[8][64];
  float creg[96];
  const float* crow = ctx + ((size_t)(b * ENC + s)) * DIM + seg * 96;
#pragma unroll
  for (int kk = 0; kk < 96; kk += 4) {
    float4 v = *(const float4*)(crow + kk);
    creg[kk] = v.x; creg[kk + 1] = v.y; creg[kk + 2] = v.z; creg[kk + 3] = v.w;
  }
  const float madd = (1.0f - mask[b * ENC + s]) * NEGF;
  const int myid = ids[b * ENC + s];
  for (int t = 0; t < Tn; ++t) {
    const int row = t * Bdim + b;
    const float* q = copyq + (size_t)row * 768 + seg * 96;  // uniform -> s_load
    float dot = 0.f;
#pragma unroll
    for (int kk = 0; kk < 96; kk += 4) {
      float4 qv = *(const float4*)(q + kk);
      dot = fmaf(qv.x, creg[kk], fmaf(qv.y, creg[kk + 1],
            fmaf(qv.z, creg[kk + 2], fmaf(qv.w, creg[kk + 3], dot))));
    }
    part[seg][lane] = dot;
    __syncthreads();
    if (threadIdx.x < 64) {
      float logit = madd;
#pragma unroll
      for (int w = 0; w < 8; ++w) logit += part[w][lane];
      float e = __expf(logit);  // |logit| <~ 60 : safe in fp32 without max-sub
      int tgt = dtg[b * Tn + t];
      float ne = (myid == tgt) ? e : 0.f;
      float dsum = wred_sum(e);
      float nsum = wred_sum(ne);
      if (lane == 0) {
        atomicAdd(&cden[row], dsum);
        if (nsum != 0.f) atomicAdd(&cnum[row], nsum);
      }
    }
    __syncthreads();
  }
}

// ---- deferred: vocab exp-sum per row. grid (83, 16) x 256, 64 rows/block ----
__global__ void __launch_bounds__(256) k_vocab(
    const float* __restrict__ emb, const float* __restrict__ out_all,
    float* __restrict__ S) {
  const int vc = blockIdx.x, tbc = blockIdx.y;
  const int tb0 = tbc * 64;
  const int v = vc * 256 + threadIdx.x;
  const bool valid = v < VOCAB;
  const int vv = valid ? v : 0;
  __shared__ float rowsum[64];
  if (threadIdx.x < 64) rowsum[threadIdx.x] = 0.f;
  __syncthreads();
  float acc[64];
#pragma unroll
  for (int i = 0; i < 64; ++i) acc[i] = 0.f;
  const float* erow = emb + (size_t)vv * DIM;
  for (int k = 0; k < DIM; k += 4) {
    float4 w = *(const float4*)(erow + k);
#pragma unroll
    for (int i = 0; i < 64; ++i) {
      float4 a = *(const float4*)(out_all + (size_t)(tb0 + i) * DIM + k);  // uniform -> s_load
      acc[i] = fmaf(w.x, a.x, fmaf(w.y, a.y, fmaf(w.z, a.z, fmaf(w.w, a.w, acc[i]))));
    }
  }
  const int lane = threadIdx.x & 63;
#pragma unroll
  for (int i = 0; i < 64; ++i) {
    float e = valid ? __expf(acc[i]) : 0.f;  // logits ~O(1): no max-sub needed
    float r = wred_sum(e);
    if (lane == 0) atomicAdd(&rowsum[i], r);
  }
  __syncthreads();
  if (threadIdx.x < 64) atomicAdd(&S[tb0 + threadIdx.x], rowsum[threadIdx.x]);
}

// ---- deferred: per-row target prob + loss accumulation. grid 16 x 256 ----
__global__ void k_tgt(
    const int* __restrict__ dtg, const float* __restrict__ out_all,
    const float* __restrict__ emb, const float* __restrict__ Wm,
    const float* __restrict__ bm, const float* __restrict__ h_all,
    const float* __restrict__ S, const float* __restrict__ cnum,
    const float* __restrict__ cden, float* __restrict__ loss) {
  const int lane = threadIdx.x & 63;
  const int w = __builtin_amdgcn_readfirstlane(threadIdx.x >> 6);
  for (int rr = 0; rr < 16; ++rr) {
    const int row = (blockIdx.x * 4 + w) * 16 + rr;
    const int t = row >> 4, b = row & 15;
    const int tgt = dtg[b * Tn + t];
    const float* orow = out_all + (size_t)row * DIM + lane * 12;
    const float* erow = emb + (size_t)tgt * DIM + lane * 12;
    const float* hrow = h_all + (size_t)(row + 16) * DIM + lane * 12;
    const float* wm = Wm + lane * 12;
    float lt = 0.f, md = 0.f;
#pragma unroll
    for (int k = 0; k < 12; k += 4) {
      float4 o = *(const float4*)(orow + k);
      float4 e = *(const float4*)(erow + k);
      float4 h = *(const float4*)(hrow + k);
      float4 m = *(const float4*)(wm + k);
      lt = fmaf(o.x, e.x, fmaf(o.y, e.y, fmaf(o.z, e.z, fmaf(o.w, e.w, lt))));
      md = fmaf(m.x, h.x, fmaf(m.y, h.y, fmaf(m.z, h.z, fmaf(m.w, h.w, md))));
    }
    lt = wred_sum(lt);
    md = wred_sum(md);
    if (lane == 0 && tgt != 0) {
      float mode = sigmf(md + bm[0]);
      float pv = __expf(lt) / S[row] * mode;
      float den = cden[row];
      float pc = (den > 0.f) ? (cnum[row] / den) : 0.f;
      float p = pv + (1.0f - mode) * pc;
      atomicAdd(&loss[0], -logf(p + 1e-6f));
      atomicAdd(&loss[1], 1.0f);
    }
  }
}

__global__ void k_write(const float* __restrict__ loss, float* __restrict__ out) {
  if (threadIdx.x < Bdim) out[threadIdx.x] = loss[0] / loss[1];
}

extern "C" void kernel_launch(void* const* d_in, const int* in_sizes, int n_in,
                              void* d_out, int out_size, void* d_ws, size_t ws_size,
                              hipStream_t stream) {
  (void)in_sizes; (void)n_in; (void)out_size; (void)ws_size;
  const int*   input_ids = (const int*)d_in[0];
  const float* ctx       = (const float*)d_in[1];
  const float* cmask     = (const float*)d_in[2];
  const int*   din       = (const int*)d_in[3];
  const int*   dtg       = (const int*)d_in[4];
  // d_in[5], d_in[6]: use_beam_search / beam_width — unused by the reference path
  const float* embW      = (const float*)d_in[7];
  const float* Wr = (const float*)d_in[8];  const float* br  = (const float*)d_in[9];
  const float* Wu = (const float*)d_in[10]; const float* bu  = (const float*)d_in[11];
  const float* Wc = (const float*)d_in[12]; const float* bc  = (const float*)d_in[13];
  const float* Wo = (const float*)d_in[14]; const float* bo  = (const float*)d_in[15];
  const float* Wcp= (const float*)d_in[16]; const float* bcp = (const float*)d_in[17];
  const float* Wm = (const float*)d_in[18]; const float* bm  = (const float*)d_in[19];
  const float* ih = (const float*)d_in[20];

  float* ws      = (float*)d_ws;
  float* P_ru    = ws;                          // 1024*1536
  float* P_c     = P_ru + 1024 * 1536;          // 1024*768
  float* h_all   = P_c + 1024 * 768;            // 65*16*768
  float* attn    = h_all + 65 * 16 * 768;       // 16*768
  float* out_all = attn + 16 * 768;             // 1024*768
  float* copyq   = out_all + 1024 * 768;        // 1024*768
  float* S       = copyq + 1024 * 768;          // 1024
  float* cnum    = S + 1024;                    // 1024
  float* cden    = cnum + 1024;                 // 1024
  float* loss    = cden + 1024;                 // 2
  // total 4,746,242 floats = 18.99 MB of ws

  k_zero<<<4, 1024, 0, stream>>>(S, 1024 * 3 + 2);
  k_h0<<<12, 1024, 0, stream>>>(ih, h_all);
  k_pre<<<dim3(9, 64), 256, 0, stream>>>(din, embW, Wr, br, Wu, bu, Wc, bc, P_ru, P_c);

  for (int t = 0; t < Tn; ++t) {
    k_attn<<<16, 512, 0, stream>>>(t, ctx, cmask, P_ru, P_c, h_all, attn);
    k_ru<<<dim3(6, 16), 256, 0, stream>>>(t, Wr, Wu, attn, h_all, P_ru);
    k_c<<<dim3(3, 16), 256, 0, stream>>>(t, Wc, attn, h_all, P_ru, P_c);
  }
  k_hfin<<<16, 256, 0, stream>>>(P_ru, P_c, h_all);

  k_out<<<dim3(6, 64), 256, 0, stream>>>(Wo, bo, Wcp, bcp, h_all, out_all, copyq);
  k_copy<<<dim3(8, 16), 512, 0, stream>>>(input_ids, dtg, ctx, cmask, copyq, cnum, cden);
  k_vocab<<<dim3(83, 16), 256, 0, stream>>>(embW, out_all, S);
  k_tgt<<<16, 256, 0, stream>>>(dtg, out_all, embW, Wm, bm, h_all, S, cnum, cden, loss);
  k_write<<<1, 64, 0, stream>>>(loss, (float*)d_out);
}

// Round 2
// 10444.821 us; speedup vs baseline: 1.1596x; 1.1596x over previous
//
#include <hip/hip_runtime.h>
#include <hip/hip_bf16.h>
#include <math.h>

// Problem constants (GRUAttnDecoder): B=16, ENC=512, T=64, DIM=768, VOCAB=21128
#define Bdim 16
#define ENC 512
#define Tn 64
#define DIM 768
#define VOCAB 21128
#define SCALEF 0.03608439182435161f  // 1/sqrt(768)
#define NEGF   -1e30f
#define NBLK 256

__device__ __forceinline__ float wred_sum(float v) {
#pragma unroll
  for (int m = 32; m >= 1; m >>= 1) v += __shfl_xor(v, m, 64);
  return v;
}
__device__ __forceinline__ float sigmf(float x) { return 1.0f / (1.0f + __expf(-x)); }

// one-shot grid barrier: bar[idx] pre-zeroed, each barrier index used exactly once
__device__ __forceinline__ void gbar(int* bar, int idx) {
  __syncthreads();
  if (threadIdx.x == 0) {
    __threadfence();  // release: flush this block's writes to coherent point
    __hip_atomic_fetch_add(&bar[idx], 1, __ATOMIC_RELAXED, __HIP_MEMORY_SCOPE_AGENT);
    while (__hip_atomic_load(&bar[idx], __ATOMIC_RELAXED, __HIP_MEMORY_SCOPE_AGENT) < NBLK) {
      __builtin_amdgcn_s_sleep(4);
    }
    __threadfence();  // acquire: invalidate stale L1/L2 before reading others' data
  }
  __syncthreads();
}

// ---------------- init ----------------
__global__ void k_zero(float* __restrict__ p, int n) {
  int i = blockIdx.x * blockDim.x + threadIdx.x;
  int stride = gridDim.x * blockDim.x;
  for (; i < n; i += stride) p[i] = 0.0f;
}

__global__ void k_h0(const float* __restrict__ init_h, float* __restrict__ h_all) {
  int i = blockIdx.x * blockDim.x + threadIdx.x;
  if (i < Bdim * DIM) h_all[i] = init_h[i % DIM];
}

// ---- precompute emb-part of gate preactivations + bias for all (t,b) ----
// grid (9, 64) x 256
__global__ void __launch_bounds__(256, 2) k_pre(
    const int* __restrict__ din, const float* __restrict__ emb,
    const float* __restrict__ Wr, const float* __restrict__ br,
    const float* __restrict__ Wu, const float* __restrict__ bu,
    const float* __restrict__ Wc, const float* __restrict__ bc,
    float* __restrict__ P_ru, float* __restrict__ P_c) {
  const int nb = blockIdx.x, tbc = blockIdx.y;
  const int n = nb * 256 + threadIdx.x;
  const float* wrow;
  float bias;
  if (n < 768)       { wrow = Wr + n * 2304 + 768;          bias = br[n]; }
  else if (n < 1536) { wrow = Wu + (n - 768) * 2304 + 768;  bias = bu[n - 768]; }
  else               { wrow = Wc + (n - 1536) * 2304 + 768; bias = bc[n - 1536]; }
  int id[16];
#pragma unroll
  for (int i = 0; i < 16; ++i) {
    int row = tbc * 16 + i;                 // row = t*16 + b
    id[i] = din[(row & 15) * Tn + (row >> 4)];
  }
  float acc[16];
#pragma unroll
  for (int i = 0; i < 16; ++i) acc[i] = bias;
  for (int k = 0; k < DIM; k += 4) {
    float4 w = *(const float4*)(wrow + k);
#pragma unroll
    for (int i = 0; i < 16; ++i) {
      float4 x = *(const float4*)(emb + (size_t)id[i] * DIM + k);
      acc[i] = fmaf(w.x, x.x, fmaf(w.y, x.y, fmaf(w.z, x.z, fmaf(w.w, x.w, acc[i]))));
    }
  }
#pragma unroll
  for (int i = 0; i < 16; ++i) {
    int row = tbc * 16 + i;
    if (n < 1536) P_ru[(size_t)row * 1536 + n] = acc[i];
    else          P_c[(size_t)row * 768 + (n - 1536)] = acc[i];
  }
}

// ---- persistent sequential kernel: whole T-loop, 256 blocks x 512 threads ----
// attention partition: block = (b = bid>>4, s-chunk = bid&15, 32 s each)
// gate partition:      block = (row-group rg = bid>>2, batch-quad bq = bid&3)
__global__ void __launch_bounds__(512, 2) k_seq(
    const float* __restrict__ ctx, const float* __restrict__ mask,
    const float* __restrict__ Wr, const float* __restrict__ Wu,
    const float* __restrict__ Wc,
    const float* __restrict__ P_ru, const float* __restrict__ P_c,
    float* __restrict__ h_all, float* __restrict__ attnacc,
    float* __restrict__ den, float* __restrict__ r_buf,
    float* __restrict__ u_buf, int* __restrict__ bar) {
  const int bid = blockIdx.x;
  const int tid = threadIdx.x;
  const int lane = tid & 63;
  const int wv = tid >> 6;           // 0..7
  const int b_a = bid >> 4;          // attention batch
  const int sc = bid & 15;           // s-chunk
  const int bq = bid & 3;            // gate batch quad (batches bq*4..bq*4+3)
  const int rg = bid >> 2;           // gate row group 0..63

  __shared__ float x_lds[4 * 1536];  // [b in quad][a(768) | h or r*h (768)]
  __shared__ float h_lds[DIM];
  __shared__ float e_lds[32];
  __shared__ float madd_lds[32];

  for (int i = tid; i < 32; i += 512)
    madd_lds[i] = (1.0f - mask[b_a * ENC + sc * 32 + i]) * NEGF;

  int bidx = 0;
  for (int t = 0; t < Tn; ++t) {
    const int p = t & 1;
    // ================= phase A: attention =================
    for (int i = tid; i < DIM; i += 512)
      h_lds[i] = h_all[(size_t)(t * Bdim + b_a) * DIM + i];
    __syncthreads();
    {
      float esum = 0.f;
#pragma unroll
      for (int i = 0; i < 4; ++i) {
        const int r = wv * 4 + i;
        const int s = sc * 32 + r;
        const float* crow = ctx + ((size_t)(b_a * ENC + s)) * DIM;
        float dot = 0.f;
#pragma unroll
        for (int j = 0; j < 12; ++j) {
          int k = lane + 64 * j;
          dot = fmaf(crow[k], h_lds[k], dot);
        }
        dot = wred_sum(dot);
        float e = __expf(fmaf(dot, SCALEF, madd_lds[r]));  // scores O(1): no max-sub
        if (lane == 0) e_lds[r] = e;
        esum += e;
      }
      if (lane == 0) atomicAdd(&den[p * Bdim + b_a], esum);
    }
    __syncthreads();
    // weighted partial sum of ctx rows -> attnacc (unnormalized)
    for (int c = tid; c < DIM; c += 512) {
      float acc = 0.f;
      const float* cb = ctx + ((size_t)(b_a * ENC + sc * 32)) * DIM + c;
#pragma unroll 8
      for (int r = 0; r < 32; ++r)
        acc = fmaf(e_lds[r], cb[(size_t)r * DIM], acc);
      atomicAdd(&attnacc[((size_t)(p * Bdim + b_a)) * DIM + c], acc);
    }
    gbar(bar, bidx++);

    // ================= phase B: r,u gates =================
    // stage x = [a | h] for the 4 batches of this block's quad
    for (int idx = tid; idx < 4 * 1536; idx += 512) {
      int b = idx / 1536;
      int k = idx - b * 1536;
      int bb = bq * 4 + b;
      float v;
      if (k < 768) v = attnacc[((size_t)(p * Bdim + bb)) * DIM + k] / den[p * Bdim + bb];
      else         v = h_all[(size_t)(t * Bdim + bb) * DIM + (k - 768)];
      x_lds[idx] = v;
    }
    __syncthreads();
    {
      const int r0 = rg * 24 + wv * 3;
#pragma unroll
      for (int rr = 0; rr < 3; ++rr) {
        const int row = r0 + rr;  // 0..1535 : r rows then u rows
        const float* wbase = (row < 768) ? (Wr + (size_t)row * 2304)
                                         : (Wu + (size_t)(row - 768) * 2304);
        float a0 = 0.f, a1 = 0.f, a2 = 0.f, a3 = 0.f;
#pragma unroll
        for (int j = 0; j < 24; ++j) {
          int xk = lane + 64 * j;
          int wcol = (j < 12) ? xk : (xk + 768);  // x h-slot -> W cols 1536..2303
          float w = wbase[wcol];
          a0 = fmaf(w, x_lds[0 * 1536 + xk], a0);
          a1 = fmaf(w, x_lds[1 * 1536 + xk], a1);
          a2 = fmaf(w, x_lds[2 * 1536 + xk], a2);
          a3 = fmaf(w, x_lds[3 * 1536 + xk], a3);
        }
        a0 = wred_sum(a0); a1 = wred_sum(a1); a2 = wred_sum(a2); a3 = wred_sum(a3);
        if (lane < 4) {
          float av = (lane == 0) ? a0 : (lane == 1) ? a1 : (lane == 2) ? a2 : a3;
          int bb = bq * 4 + lane;
          float pre = P_ru[(size_t)(t * Bdim + bb) * 1536 + row] + av;
          float s = sigmf(pre);
          if (row < 768) r_buf[bb * DIM + row] = s;
          else           u_buf[bb * DIM + (row - 768)] = s;
        }
      }
    }
    gbar(bar, bidx++);

    // ================= phase C: c gate + h update =================
    // x h-slot *= r  (making it r*h); also zero next-parity attn buffers
    for (int idx = tid; idx < 4 * 768; idx += 512) {
      int b = idx / 768;
      int k = idx - b * 768;
      x_lds[b * 1536 + 768 + k] *= r_buf[(bq * 4 + b) * DIM + k];
    }
    {
      const int pz = 1 - p;
      int g = bid * 512 + tid;
      if (g < Bdim * DIM) attnacc[(size_t)pz * Bdim * DIM + g] = 0.f;
      if (g < Bdim) den[pz * Bdim + g] = 0.f;
    }
    __syncthreads();
    if (wv < 4) {
      const int r0 = rg * 12 + wv * 3;
#pragma unroll
      for (int rr = 0; rr < 3; ++rr) {
        const int row = r0 + rr;  // 0..767
        const float* wbase = Wc + (size_t)row * 2304;
        float a0 = 0.f, a1 = 0.f, a2 = 0.f, a3 = 0.f;
#pragma unroll
        for (int j = 0; j < 24; ++j) {
          int xk = lane + 64 * j;
          int wcol = (j < 12) ? xk : (xk + 768);
          float w = wbase[wcol];
          a0 = fmaf(w, x_lds[0 * 1536 + xk], a0);
          a1 = fmaf(w, x_lds[1 * 1536 + xk], a1);
          a2 = fmaf(w, x_lds[2 * 1536 + xk], a2);
          a3 = fmaf(w, x_lds[3 * 1536 + xk], a3);
        }
        a0 = wred_sum(a0); a1 = wred_sum(a1); a2 = wred_sum(a2); a3 = wred_sum(a3);
        if (lane < 4) {
          float av = (lane == 0) ? a0 : (lane == 1) ? a1 : (lane == 2) ? a2 : a3;
          int bb = bq * 4 + lane;
          float c = tanhf(P_c[(size_t)(t * Bdim + bb) * 768 + row] + av);
          float hp = h_all[(size_t)(t * Bdim + bb) * DIM + row];
          float u = u_buf[bb * DIM + row];
          h_all[(size_t)((t + 1) * Bdim + bb) * DIM + row] = hp + u * (c - hp);
        }
      }
    }
    gbar(bar, bidx++);
  }
}

// ---- deferred: out_all & copyq for all 1024 rows ----
__global__ void __launch_bounds__(256, 2) k_out(
    const float* __restrict__ Wo, const float* __restrict__ bo,
    const float* __restrict__ Wcp, const float* __restrict__ bcp,
    const float* __restrict__ h_all, float* __restrict__ out_all,
    float* __restrict__ copyq) {
  const int nb = blockIdx.x, tbc = blockIdx.y;
  const int n = nb * 256 + threadIdx.x;  // 0..1535
  const float* wrow;
  float bias;
  if (n < 768) { wrow = Wo + (size_t)n * 768;          bias = bo[n]; }
  else         { wrow = Wcp + (size_t)(n - 768) * 768; bias = bcp[n - 768]; }
  const float* hbase = h_all + (size_t)(tbc * 16 + 16) * DIM;  // h_new = slot t+1
  float acc[16];
#pragma unroll
  for (int i = 0; i < 16; ++i) acc[i] = bias;
  for (int k = 0; k < DIM; k += 4) {
    float4 w = *(const float4*)(wrow + k);
#pragma unroll
    for (int i = 0; i < 16; ++i) {
      float4 x = *(const float4*)(hbase + i * DIM + k);
      acc[i] = fmaf(w.x, x.x, fmaf(w.y, x.y, fmaf(w.z, x.z, fmaf(w.w, x.w, acc[i]))));
    }
  }
#pragma unroll
  for (int i = 0; i < 16; ++i) {
    int row = tbc * 16 + i;
    if (n < 768) out_all[(size_t)row * 768 + n] = acc[i];
    else         copyq[(size_t)row * 768 + (n - 768)] = acc[i];
  }
}

// ---- deferred: copy softmax num/den per (t,b) ----
__global__ void __launch_bounds__(512, 2) k_copy(
    const int* __restrict__ ids, const int* __restrict__ dtg,
    const float* __restrict__ ctx, const float* __restrict__ mask,
    const float* __restrict__ copyq,
    float* __restrict__ cnum, float* __restrict__ cden) {
  const int sc = blockIdx.x, b = blockIdx.y;
  const int lane = threadIdx.x & 63;
  const int seg = __builtin_amdgcn_readfirstlane(threadIdx.x >> 6);
  const int s = sc * 64 + lane;
  __shared__ float part[8][64];
  float creg[96];
  const float* crow = ctx + ((size_t)(b * ENC + s)) * DIM + seg * 96;
#pragma unroll
  for (int kk = 0; kk < 96; kk += 4) {
    float4 v = *(const float4*)(crow + kk);
    creg[kk] = v.x; creg[kk + 1] = v.y; creg[kk + 2] = v.z; creg[kk + 3] = v.w;
  }
  const float madd = (1.0f - mask[b * ENC + s]) * NEGF;
  const int myid = ids[b * ENC + s];
  for (int t = 0; t < Tn; ++t) {
    const int row = t * Bdim + b;
    const float* q = copyq + (size_t)row * 768 + seg * 96;
    float dot = 0.f;
#pragma unroll
    for (int kk = 0; kk < 96; kk += 4) {
      float4 qv = *(const float4*)(q + kk);
      dot = fmaf(qv.x, creg[kk], fmaf(qv.y, creg[kk + 1],
            fmaf(qv.z, creg[kk + 2], fmaf(qv.w, creg[kk + 3], dot))));
    }
    part[seg][lane] = dot;
    __syncthreads();
    if (threadIdx.x < 64) {
      float logit = madd;
#pragma unroll
      for (int w = 0; w < 8; ++w) logit += part[w][lane];
      float e = __expf(logit);
      int tgt = dtg[b * Tn + t];
      float ne = (myid == tgt) ? e : 0.f;
      float dsum = wred_sum(e);
      float nsum = wred_sum(ne);
      if (lane == 0) {
        atomicAdd(&cden[row], dsum);
        if (nsum != 0.f) atomicAdd(&cnum[row], nsum);
      }
    }
    __syncthreads();
  }
}

// ---- deferred: vocab exp-sum per row. grid (83, 32) x 256, 32 rows/block ----
__global__ void __launch_bounds__(256, 1) k_vocab(
    const float* __restrict__ emb, const float* __restrict__ out_all,
    float* __restrict__ S) {
  const int vc = blockIdx.x, tbc = blockIdx.y;
  const int tb0 = tbc * 32;
  const int v = vc * 256 + threadIdx.x;
  const bool valid = v < VOCAB;
  const int vv = valid ? v : 0;
  float acc[32];
#pragma unroll
  for (int i = 0; i < 32; ++i) acc[i] = 0.f;
  const float* erow = emb + (size_t)vv * DIM;
  for (int k = 0; k < DIM; k += 4) {
    float4 w = *(const float4*)(erow + k);
#pragma unroll
    for (int i = 0; i < 32; ++i) {
      float4 a = *(const float4*)(out_all + (size_t)(tb0 + i) * DIM + k);  // uniform
      acc[i] = fmaf(w.x, a.x, fmaf(w.y, a.y, fmaf(w.z, a.z, fmaf(w.w, a.w, acc[i]))));
    }
  }
  __shared__ float rowsum[32];
  if (threadIdx.x < 32) rowsum[threadIdx.x] = 0.f;
  __syncthreads();
  const int lane = threadIdx.x & 63;
#pragma unroll
  for (int i = 0; i < 32; ++i) {
    float e = valid ? __expf(acc[i]) : 0.f;
    float r = wred_sum(e);
    if (lane == 0) atomicAdd(&rowsum[i], r);
  }
  __syncthreads();
  if (threadIdx.x < 32) atomicAdd(&S[tb0 + threadIdx.x], rowsum[threadIdx.x]);
}

// ---- deferred: per-row target prob + loss accumulation ----
__global__ void k_tgt(
    const int* __restrict__ dtg, const float* __restrict__ out_all,
    const float* __restrict__ emb, const float* __restrict__ Wm,
    const float* __restrict__ bm, const float* __restrict__ h_all,
    const float* __restrict__ S, const float* __restrict__ cnum,
    const float* __restrict__ cden, float* __restrict__ loss) {
  const int lane = threadIdx.x & 63;
  const int w = __builtin_amdgcn_readfirstlane(threadIdx.x >> 6);
  for (int rr = 0; rr < 16; ++rr) {
    const int row = (blockIdx.x * 4 + w) * 16 + rr;
    const int t = row >> 4, b = row & 15;
    const int tgt = dtg[b * Tn + t];
    const float* orow = out_all + (size_t)row * DIM + lane * 12;
    const float* erow = emb + (size_t)tgt * DIM + lane * 12;
    const float* hrow = h_all + (size_t)(row + 16) * DIM + lane * 12;
    const float* wm = Wm + lane * 12;
    float lt = 0.f, md = 0.f;
#pragma unroll
    for (int k = 0; k < 12; k += 4) {
      float4 o = *(const float4*)(orow + k);
      float4 e = *(const float4*)(erow + k);
      float4 h = *(const float4*)(hrow + k);
      float4 m = *(const float4*)(wm + k);
      lt = fmaf(o.x, e.x, fmaf(o.y, e.y, fmaf(o.z, e.z, fmaf(o.w, e.w, lt))));
      md = fmaf(m.x, h.x, fmaf(m.y, h.y, fmaf(m.z, h.z, fmaf(m.w, h.w, md))));
    }
    lt = wred_sum(lt);
    md = wred_sum(md);
    if (lane == 0 && tgt != 0) {
      float mode = sigmf(md + bm[0]);
      float pv = __expf(lt) / S[row] * mode;
      float den = cden[row];
      float pc = (den > 0.f) ? (cnum[row] / den) : 0.f;
      float p = pv + (1.0f - mode) * pc;
      atomicAdd(&loss[0], -logf(p + 1e-6f));
      atomicAdd(&loss[1], 1.0f);
    }
  }
}

__global__ void k_write(const float* __restrict__ loss, float* __restrict__ out) {
  if (threadIdx.x < Bdim) out[threadIdx.x] = loss[0] / loss[1];
}

extern "C" void kernel_launch(void* const* d_in, const int* in_sizes, int n_in,
                              void* d_out, int out_size, void* d_ws, size_t ws_size,
                              hipStream_t stream) {
  (void)in_sizes; (void)n_in; (void)out_size; (void)ws_size;
  const int*   input_ids = (const int*)d_in[0];
  const float* ctx       = (const float*)d_in[1];
  const float* cmask     = (const float*)d_in[2];
  const int*   din       = (const int*)d_in[3];
  const int*   dtg       = (const int*)d_in[4];
  const float* embW      = (const float*)d_in[7];
  const float* Wr = (const float*)d_in[8];  const float* br  = (const float*)d_in[9];
  const float* Wu = (const float*)d_in[10]; const float* bu  = (const float*)d_in[11];
  const float* Wc = (const float*)d_in[12]; const float* bc  = (const float*)d_in[13];
  const float* Wo = (const float*)d_in[14]; const float* bo  = (const float*)d_in[15];
  const float* Wcp= (const float*)d_in[16]; const float* bcp = (const float*)d_in[17];
  const float* Wm = (const float*)d_in[18]; const float* bm  = (const float*)d_in[19];
  const float* ih = (const float*)d_in[20];

  float* ws      = (float*)d_ws;
  float* P_ru    = ws;                          // 1024*1536
  float* P_c     = P_ru + 1024 * 1536;          // 1024*768
  float* h_all   = P_c + 1024 * 768;            // 65*16*768
  float* out_all = h_all + 65 * 16 * 768;       // 1024*768
  float* copyq   = out_all + 1024 * 768;        // 1024*768
  float* r_buf   = copyq + 1024 * 768;          // 16*768
  float* u_buf   = r_buf + 16 * 768;            // 16*768
  float* S       = u_buf + 16 * 768;            // 1024   } zero region start
  float* cnum    = S + 1024;                    // 1024
  float* cden    = cnum + 1024;                 // 1024
  float* loss    = cden + 1024;                 // 2
  float* attnacc = loss + 2;                    // 2*16*768
  float* den     = attnacc + 2 * 16 * 768;      // 2*16
  int*   bar     = (int*)(den + 2 * 16);        // 256 ints
  const int nzero = 1024 * 3 + 2 + 2 * 16 * 768 + 2 * 16 + 256;  // 28962

  k_zero<<<8, 1024, 0, stream>>>(S, nzero);
  k_h0<<<12, 1024, 0, stream>>>(ih, h_all);
  k_pre<<<dim3(9, 64), 256, 0, stream>>>(din, embW, Wr, br, Wu, bu, Wc, bc, P_ru, P_c);

  k_seq<<<NBLK, 512, 0, stream>>>(ctx, cmask, Wr, Wu, Wc, P_ru, P_c,
                                  h_all, attnacc, den, r_buf, u_buf, bar);

  k_out<<<dim3(6, 64), 256, 0, stream>>>(Wo, bo, Wcp, bcp, h_all, out_all, copyq);
  k_copy<<<dim3(8, 16), 512, 0, stream>>>(input_ids, dtg, ctx, cmask, copyq, cnum, cden);
  k_vocab<<<dim3(83, 32), 256, 0, stream>>>(embW, out_all, S);
  k_tgt<<<16, 256, 0, stream>>>(dtg, out_all, embW, Wm, bm, h_all, S, cnum, cden, loss);
  k_write<<<1, 64, 0, stream>>>(loss, (float*)d_out);
}